// Round 2
// baseline (94.769 us; speedup 1.0000x reference)
//
#include <hip/hip_runtime.h>

// Match XLA's elementwise f32 exactly: no FMA contraction on the decision path.
#pragma clang fp contract(off)

#define N_BOX   10647
#define N_CLS   80
#define ROW     85
#define CONF_T  0.8f
#define NMS_T   0.4f
#define NEGV    -1000000000.0f
#define KMAX    256       // max boxes per class (expected ~27, max ~50)
#define OUT_N   3000
#define SURV_N  4096      // survivors cap (expected ~2000)
#define ROWS_PB 128       // rows per block in stage1

struct Rec { float x1, y1, x2, y2, score, conf; int idx, pad; };

// counters[0..79] = per-class counts, counters[80] = survivor count
#define N_CTR 81

// Stage 0: zero counters + pre-fill output with NEG.
__global__ __launch_bounds__(256) void k_init(int* __restrict__ counters,
                                              float* __restrict__ out) {
    int t = blockIdx.x * blockDim.x + threadIdx.x;
    if (t < N_CTR) counters[t] = 0;
    if (t < OUT_N) out[t] = NEGV;
}

// Stage 1: batch 0 only. Coalesced LDS staging, filter obj>=0.8,
// cls max/argmax, xyxy, bin directly per class.
__global__ __launch_bounds__(256) void k_stage1(const float* __restrict__ det,
                                                Rec* __restrict__ bins,
                                                int* __restrict__ counters) {
    __shared__ float lds[ROWS_PB * ROW];   // 43520 B
    const int tid = threadIdx.x;
    const int row0 = blockIdx.x * ROWS_PB;
    int nrows = N_BOX - row0; if (nrows > ROWS_PB) nrows = ROWS_PB;
    if (nrows <= 0) return;

    const int nflt = nrows * ROW;
    const float* src = det + (size_t)row0 * ROW;
    for (int j = tid; j < nflt; j += 256) lds[j] = src[j];
    __syncthreads();

    if (tid < nrows) {
        const float* p = lds + tid * ROW;
        float obj = p[4];
        if (obj >= CONF_T) {
            float cx = p[0], cy = p[1], w = p[2], h = p[3];
            float hw = w / 2.0f, hh = h / 2.0f;
            // first-argmax over 80 classes (strict > keeps first, = jnp.argmax)
            float best = p[5]; int bid = 0;
            for (int c = 1; c < N_CLS; ++c) {
                float v = p[5 + c];
                if (v > best) { best = v; bid = c; }
            }
            int pos = atomicAdd(&counters[bid], 1);
            if (pos < KMAX) {
                Rec r;
                r.x1 = cx - hw; r.y1 = cy - hh; r.x2 = cx + hw; r.y2 = cy + hh;
                r.score = obj * best; r.conf = best; r.idx = row0 + tid; r.pad = 0;
                bins[bid * KMAX + pos] = r;
            }
        }
    }
}

// Stage 2: one WAVE (64 threads) per class. Sort by (score desc, idx asc),
// greedy NMS with the reference's exact IoU, append survivor confs.
__global__ __launch_bounds__(64) void k_nms(const Rec* __restrict__ bins,
                                            int* __restrict__ counters,
                                            float* __restrict__ surv) {
    const int c = blockIdx.x;
    const int tid = threadIdx.x;

    __shared__ float rsc[KMAX]; __shared__ int ridx[KMAX];
    __shared__ float sx1[KMAX], sy1[KMAX], sx2[KMAX], sy2[KMAX], scf[KMAX];
    __shared__ unsigned char alive[KMAX];
    __shared__ float keepc[KMAX];
    __shared__ int nkeep, base;

    if (tid == 0) nkeep = 0;
    int k = counters[c]; if (k > KMAX) k = KMAX;

    // stage scores/idx for ranking
    for (int i = tid; i < k; i += 64) {
        const Rec& r = bins[c * KMAX + i];
        rsc[i] = r.score; ridx[i] = r.idx;
    }
    __syncthreads();

    // rank = #{j : score[j] > score[i] or (==, idx[j] < idx[i])} -> stable desc
    for (int i = tid; i < k; i += 64) {
        float s = rsc[i]; int id = ridx[i]; int r = 0;
        for (int j = 0; j < k; ++j) {
            float sj = rsc[j];
            r += (sj > s) || (sj == s && ridx[j] < id);
        }
        const Rec& rec = bins[c * KMAX + i];
        sx1[r] = rec.x1; sy1[r] = rec.y1; sx2[r] = rec.x2; sy2[r] = rec.y2;
        scf[r] = rec.conf;
        alive[r] = 1;
    }
    __syncthreads();

    // greedy NMS (1-wave block: barriers are cheap)
    for (int i = 0; i < k; ++i) {
        __syncthreads();
        bool a = (alive[i] != 0);
        __syncthreads();
        if (a) {
            if (tid == 0) { keepc[nkeep++] = scf[i]; alive[i] = 0; }
            float bx1 = sx1[i], by1 = sy1[i], bx2 = sx2[i], by2 = sy2[i];
            float a1 = ((bx2 - bx1) + 1.0f) * ((by2 - by1) + 1.0f);
            for (int j = i + 1 + tid; j < k; j += 64) {
                if (!alive[j]) continue;
                float ix1 = fmaxf(bx1, sx1[j]);
                float iy1 = fmaxf(by1, sy1[j]);
                float ix2 = fminf(bx2, sx2[j]);
                float iy2 = fminf(by2, sy2[j]);
                float iw = fmaxf((ix2 - ix1) + 1.0f, 0.0f);
                float ih = fmaxf((iy2 - iy1) + 1.0f, 0.0f);
                float inter = iw * ih;
                float a2 = ((sx2[j] - sx1[j]) + 1.0f) * ((sy2[j] - sy1[j]) + 1.0f);
                float den = ((a1 + a2) - inter) + 1e-16f;
                if (inter / den > NMS_T) alive[j] = 0;
            }
        }
    }
    __syncthreads();

    if (tid == 0) base = atomicAdd(&counters[80], nkeep);
    __syncthreads();
    int nb = nkeep, b = base;
    for (int i = tid; i < nb; i += 64) {
        int o = b + i;
        if (o < SURV_N) surv[o] = keepc[i];
    }
}

// Stage 3: rank-scatter sort. out was pre-filled with NEG by k_init.
__global__ __launch_bounds__(256) void k_rank(const float* __restrict__ surv,
                                              const int* __restrict__ counters,
                                              float* __restrict__ out) {
    __shared__ float s[SURV_N];
    const int tid = threadIdx.x;
    int m = counters[80]; if (m > SURV_N) m = SURV_N;
    int m4 = (m + 3) & ~3;
    for (int i = tid; i < m4; i += 256) s[i] = (i < m) ? surv[i] : NEGV;
    __syncthreads();

    int g = blockIdx.x * 256 + tid;
    if (g < m) {
        float v = s[g];
        int r = 0;
        const float4* s4 = (const float4*)s;
        for (int jj = 0; jj < (m4 >> 2); ++jj) {
            float4 a = s4[jj];
            int j0 = jj << 2;
            r += (a.x > v) || (a.x == v && (j0 + 0) < g);
            r += (a.y > v) || (a.y == v && (j0 + 1) < g);
            r += (a.z > v) || (a.z == v && (j0 + 2) < g);
            r += (a.w > v) || (a.w == v && (j0 + 3) < g);
        }
        if (r < OUT_N) out[r] = v;
    }
}

extern "C" void kernel_launch(void* const* d_in, const int* in_sizes, int n_in,
                              void* d_out, int out_size, void* d_ws, size_t ws_size,
                              hipStream_t stream) {
    const float* det = (const float*)d_in[0];
    float* out = (float*)d_out;

    int*  counters = (int*)d_ws;                                   // 81 ints
    Rec*  bins     = (Rec*)((char*)d_ws + 512);                    // 80*KMAX*32B
    float* surv    = (float*)((char*)d_ws + 512 + N_CLS * KMAX * sizeof(Rec));

    hipLaunchKernelGGL(k_init,   dim3((OUT_N + 255) / 256), dim3(256), 0, stream,
                       counters, out);
    hipLaunchKernelGGL(k_stage1, dim3((N_BOX + ROWS_PB - 1) / ROWS_PB), dim3(256), 0, stream,
                       det, bins, counters);
    hipLaunchKernelGGL(k_nms,    dim3(N_CLS), dim3(64), 0, stream,
                       bins, counters, surv);
    hipLaunchKernelGGL(k_rank,   dim3(SURV_N / 256), dim3(256), 0, stream,
                       surv, counters, out);
}

// Round 3
// 42.006 us; speedup vs baseline: 2.2561x; 2.2561x over previous
//
#include <hip/hip_runtime.h>

// Match XLA's elementwise f32 exactly: no FMA contraction on the decision path.
#pragma clang fp contract(off)

#define N_BOX   10647
#define N_CLS   80
#define ROW     85
#define CONF_T  0.8f
#define NMS_T   0.4f
#define NEGV    -1000000000.0f
#define KMAX    256       // max boxes per class (expected ~27)
#define OUT_N   3000
#define SURV_N  4096      // survivors cap (expected ~2000)
#define ROWS_PB 128       // rows per block in stage1

struct Rec { float x1, y1, x2, y2, score, conf; int idx, pad; };

// counters[0..79] = per-class counts, counters[80] = survivor count
#define N_CTR 81

// Stage 0: zero counters + pre-fill output with NEG.
__global__ __launch_bounds__(256) void k_init(int* __restrict__ counters,
                                              float* __restrict__ out) {
    int t = blockIdx.x * blockDim.x + threadIdx.x;
    if (t < N_CTR) counters[t] = 0;
    if (t < OUT_N) out[t] = NEGV;
}

// Stage 1: batch 0 only. Coalesced LDS staging, filter obj>=0.8,
// cls max/argmax, xyxy, bin directly per class.
__global__ __launch_bounds__(256) void k_stage1(const float* __restrict__ det,
                                                Rec* __restrict__ bins,
                                                int* __restrict__ counters) {
    __shared__ float lds[ROWS_PB * ROW];   // 43520 B
    const int tid = threadIdx.x;
    const int row0 = blockIdx.x * ROWS_PB;
    int nrows = N_BOX - row0; if (nrows > ROWS_PB) nrows = ROWS_PB;
    if (nrows <= 0) return;

    const int nflt = nrows * ROW;
    const float* src = det + (size_t)row0 * ROW;
    for (int j = tid; j < nflt; j += 256) lds[j] = src[j];
    __syncthreads();

    if (tid < nrows) {
        const float* p = lds + tid * ROW;
        float obj = p[4];
        if (obj >= CONF_T) {
            float cx = p[0], cy = p[1], w = p[2], h = p[3];
            float hw = w / 2.0f, hh = h / 2.0f;
            // first-argmax over 80 classes (strict > keeps first, = jnp.argmax)
            float best = p[5]; int bid = 0;
            for (int c = 1; c < N_CLS; ++c) {
                float v = p[5 + c];
                if (v > best) { best = v; bid = c; }
            }
            int pos = atomicAdd(&counters[bid], 1);
            if (pos < KMAX) {
                Rec r;
                r.x1 = cx - hw; r.y1 = cy - hh; r.x2 = cx + hw; r.y2 = cy + hh;
                r.score = obj * best; r.conf = best; r.idx = row0 + tid; r.pad = 0;
                bins[bid * KMAX + pos] = r;
            }
        }
    }
}

// Stage 2: one WAVE (64 threads) per class. Sort by (score desc, idx asc),
// greedy NMS with the reference's exact IoU, append survivor confs.
__global__ __launch_bounds__(64) void k_nms(const Rec* __restrict__ bins,
                                            int* __restrict__ counters,
                                            float* __restrict__ surv) {
    const int c = blockIdx.x;
    const int tid = threadIdx.x;

    __shared__ float rsc[KMAX]; __shared__ int ridx[KMAX];
    __shared__ float sx1[KMAX], sy1[KMAX], sx2[KMAX], sy2[KMAX], scf[KMAX];
    __shared__ unsigned char alive[KMAX];
    __shared__ float keepc[KMAX];
    __shared__ int nkeep, base;

    if (tid == 0) nkeep = 0;
    int k = counters[c]; if (k > KMAX) k = KMAX;

    for (int i = tid; i < k; i += 64) {
        const Rec& r = bins[c * KMAX + i];
        rsc[i] = r.score; ridx[i] = r.idx;
    }
    __syncthreads();

    // rank = #{j : score[j] > score[i] or (==, idx[j] < idx[i])} -> stable desc
    for (int i = tid; i < k; i += 64) {
        float s = rsc[i]; int id = ridx[i]; int r = 0;
        for (int j = 0; j < k; ++j) {
            float sj = rsc[j];
            r += (sj > s) || (sj == s && ridx[j] < id);
        }
        const Rec& rec = bins[c * KMAX + i];
        sx1[r] = rec.x1; sy1[r] = rec.y1; sx2[r] = rec.x2; sy2[r] = rec.y2;
        scf[r] = rec.conf;
        alive[r] = 1;
    }
    __syncthreads();

    // greedy NMS (1-wave block: barriers are cheap)
    for (int i = 0; i < k; ++i) {
        __syncthreads();
        bool a = (alive[i] != 0);
        __syncthreads();
        if (a) {
            if (tid == 0) { keepc[nkeep++] = scf[i]; alive[i] = 0; }
            float bx1 = sx1[i], by1 = sy1[i], bx2 = sx2[i], by2 = sy2[i];
            float a1 = ((bx2 - bx1) + 1.0f) * ((by2 - by1) + 1.0f);
            for (int j = i + 1 + tid; j < k; j += 64) {
                if (!alive[j]) continue;
                float ix1 = fmaxf(bx1, sx1[j]);
                float iy1 = fmaxf(by1, sy1[j]);
                float ix2 = fminf(bx2, sx2[j]);
                float iy2 = fminf(by2, sy2[j]);
                float iw = fmaxf((ix2 - ix1) + 1.0f, 0.0f);
                float ih = fmaxf((iy2 - iy1) + 1.0f, 0.0f);
                float inter = iw * ih;
                float a2 = ((sx2[j] - sx1[j]) + 1.0f) * ((sy2[j] - sy1[j]) + 1.0f);
                float den = ((a1 + a2) - inter) + 1e-16f;
                if (inter / den > NMS_T) alive[j] = 0;
            }
        }
    }
    __syncthreads();

    if (tid == 0) base = atomicAdd(&counters[80], nkeep);
    __syncthreads();
    int nb = nkeep, b = base;
    for (int i = tid; i < nb; i += 64) {
        int o = b + i;
        if (o < SURV_N) surv[o] = keepc[i];
    }
}

// Stage 3: rank-scatter sort, ONE WAVE PER ELEMENT (4096 waves = 1024 blocks).
// Lanes stride over survivors (L2-hot coalesced), predicate-count, shfl-reduce.
// out was pre-filled with NEG by k_init. Tied values produce identical output
// regardless of tie order, so atomic-append order doesn't affect the result.
__global__ __launch_bounds__(256) void k_rank(const float* __restrict__ surv,
                                              const int* __restrict__ counters,
                                              float* __restrict__ out) {
    const int lane = threadIdx.x & 63;
    const int g = blockIdx.x * 4 + (threadIdx.x >> 6);   // element index (wave id)

    int m = counters[80]; if (m > SURV_N) m = SURV_N;
    if (g >= m) return;

    const float v = surv[g];
    int cnt = 0;
    for (int j = lane; j < m; j += 64) {
        float sj = surv[j];
        cnt += (sj > v) || (sj == v && j < g);
    }
    #pragma unroll
    for (int off = 32; off > 0; off >>= 1) cnt += __shfl_down(cnt, off, 64);
    if (lane == 0 && cnt < OUT_N) out[cnt] = v;
}

extern "C" void kernel_launch(void* const* d_in, const int* in_sizes, int n_in,
                              void* d_out, int out_size, void* d_ws, size_t ws_size,
                              hipStream_t stream) {
    const float* det = (const float*)d_in[0];
    float* out = (float*)d_out;

    int*  counters = (int*)d_ws;                                   // 81 ints
    Rec*  bins     = (Rec*)((char*)d_ws + 512);                    // 80*KMAX*32B
    float* surv    = (float*)((char*)d_ws + 512 + N_CLS * KMAX * sizeof(Rec));

    hipLaunchKernelGGL(k_init,   dim3((OUT_N + 255) / 256), dim3(256), 0, stream,
                       counters, out);
    hipLaunchKernelGGL(k_stage1, dim3((N_BOX + ROWS_PB - 1) / ROWS_PB), dim3(256), 0, stream,
                       det, bins, counters);
    hipLaunchKernelGGL(k_nms,    dim3(N_CLS), dim3(64), 0, stream,
                       bins, counters, surv);
    hipLaunchKernelGGL(k_rank,   dim3(SURV_N / 4), dim3(256), 0, stream,
                       surv, counters, out);
}